// Round 9
// baseline (135.830 us; speedup 1.0000x reference)
//
#include <hip/hip_runtime.h>
#include <hip/hip_bf16.h>
#include <cmath>

// Problem constants (from reference)
#define BATCH   2
#define NQ      5376
#define NV      5376
#define CDIM    256
#define HEADS   8
#define HD      32
#define LEVELS  3
#define POINTS  4
#define TP      96      // HEADS*LEVELS*POINTS
#define MROWS   (BATCH*NQ)   // 10752
#define NOFF    (TP*2)       // 192
#define NQA     (NOFF+TP)    // 288 merged off||a columns

typedef __attribute__((ext_vector_type(8))) short bf16x8;
typedef __attribute__((ext_vector_type(4))) float f32x4;
typedef unsigned short u16;
typedef unsigned int   u32;

#define AS1 __attribute__((address_space(1)))
#define AS3 __attribute__((address_space(3)))

__device__ __forceinline__ void g2lds16(const void* g, void* l) {
    // async global->LDS, 16B per lane; LDS dest = wave-uniform base + lane*16
    __builtin_amdgcn_global_load_lds((const AS1 void*)g, (AS3 void*)l, 16, 0, 0);
}

__device__ __forceinline__ u16 bf_of(float f) {
    union { __hip_bfloat16 h; u16 s; } u;
    u.h = __float2bfloat16(f);
    return u.s;
}
__device__ __forceinline__ float bf_back(u16 s) {
    return __uint_as_float((u32)s << 16);
}

// convert float4 -> 4 bf16 (RNE) packed
__device__ __forceinline__ ushort4 cvt_hi(float4 v) {
    ushort4 h;
    h.x = bf_of(v.x); h.y = bf_of(v.y); h.z = bf_of(v.z); h.w = bf_of(v.w);
    return h;
}

// ---------------------------------------------------------------------------
// GEMM tiles: 64x64x32, 256 threads = 4 waves (2x2 of 32x32 wave tiles).
// fp32 sources are converted to bf16 during staging (fused split).
// All GEMMs single-product bf16 (error budget: see round-9 analysis; v is
// consumed as bf16 anyway, so the dropped lo-term is below consumer noise).
// ---------------------------------------------------------------------------
#define GBM 64
#define GBN 64
#define GBK 32

// --- kernel 1: v-GEMM (value @ Wv^T + bv -> bf16 head-major) and
//               qa-GEMM (query @ [Woff;Wa]^T + bias -> bf16 off||a), merged.
// Flattened grid, n-tile fastest. blocks [0,672): v path; [672,1512): qa.
#define VBLOCKS (168 * 4)
__global__ __launch_bounds__(256) void gemm_vqa_kernel(
    const float* __restrict__ value, const float* __restrict__ Wv,
    const float* __restrict__ bv, u16* __restrict__ vOut,
    const float* __restrict__ query, const float* __restrict__ Woff,
    const float* __restrict__ Wa,
    const float* __restrict__ boff, const float* __restrict__ ba,
    u16* __restrict__ offOut, u16* __restrict__ aOut)
{
    __shared__ u16 sA[GBM * GBK];   // 4 KB each
    __shared__ u16 sB[GBN * GBK];

    const int bid = blockIdx.x;
    const bool vpath = bid < VBLOCKS;
    int m0, n0;
    if (vpath) { m0 = (bid >> 2) * GBM;           n0 = (bid & 3) * GBN; }
    else       { const int b2 = bid - VBLOCKS;
                 m0 = (b2 / 5) * GBM;             n0 = (b2 % 5) * GBN; }

    const int tid  = threadIdx.x;
    const int lane = tid & 63;
    const int wave = tid >> 6;
    const int wr   = wave & 1;
    const int wc   = wave >> 1;
    const int qm   = lane & 15;
    const int quad = lane >> 4;

    // staging map: row = tid>>2 (0..63), k-offset = (tid&3)*8 floats
    const int srow = tid >> 2;
    const int sc   = (tid & 3) * 8;

    // A source row (fp32)
    const float* Asrc = (vpath ? value : query) + (size_t)(m0 + srow) * CDIM;
    // B source row (fp32), row-routed for the merged Woff||Wa path
    const float* Bsrc;
    if (vpath) {
        Bsrc = Wv + (size_t)(n0 + srow) * CDIM;
    } else {
        const int rg = min(n0 + srow, NQA - 1);
        Bsrc = (rg < NOFF) ? (Woff + (size_t)rg * CDIM)
                           : (Wa + (size_t)(rg - NOFF) * CDIM);
    }

    f32x4 acc[2][2];
    #pragma unroll
    for (int i = 0; i < 2; ++i)
        #pragma unroll
        for (int j = 0; j < 2; ++j)
            acc[i][j] = (f32x4){0.f, 0.f, 0.f, 0.f};

    for (int k0 = 0; k0 < CDIM; k0 += GBK) {
        // ---- stage A ----
        const float4 a0 = *reinterpret_cast<const float4*>(&Asrc[k0 + sc]);
        const float4 a1 = *reinterpret_cast<const float4*>(&Asrc[k0 + sc + 4]);
        *reinterpret_cast<ushort4*>(&sA[srow * GBK + sc])     = cvt_hi(a0);
        *reinterpret_cast<ushort4*>(&sA[srow * GBK + sc + 4]) = cvt_hi(a1);
        // ---- stage B ----
        const float4 b0 = *reinterpret_cast<const float4*>(&Bsrc[k0 + sc]);
        const float4 b1 = *reinterpret_cast<const float4*>(&Bsrc[k0 + sc + 4]);
        *reinterpret_cast<ushort4*>(&sB[srow * GBK + sc])     = cvt_hi(b0);
        *reinterpret_cast<ushort4*>(&sB[srow * GBK + sc + 4]) = cvt_hi(b1);
        __syncthreads();

        bf16x8 fa[2], fb[2];
        #pragma unroll
        for (int x = 0; x < 2; ++x) {
            const int rm = wr * 32 + x * 16 + qm;
            const int rn = wc * 32 + x * 16 + qm;
            fa[x] = *reinterpret_cast<const bf16x8*>(&sA[rm * GBK + quad * 8]);
            fb[x] = *reinterpret_cast<const bf16x8*>(&sB[rn * GBK + quad * 8]);
        }
        #pragma unroll
        for (int mi = 0; mi < 2; ++mi)
            #pragma unroll
            for (int ni = 0; ni < 2; ++ni)
                acc[mi][ni] = __builtin_amdgcn_mfma_f32_16x16x32_bf16(
                    fa[mi], fb[ni], acc[mi][ni], 0, 0, 0);
        __syncthreads();
    }

    // epilogue: C/D layout col = lane&15 (n), row = quad*4 + reg (m)
    #pragma unroll
    for (int mi = 0; mi < 2; ++mi) {
        #pragma unroll
        for (int ni = 0; ni < 2; ++ni) {
            const int n = n0 + wc * 32 + ni * 16 + qm;
            if (vpath) {
                const float bn = bv[n];
                #pragma unroll
                for (int r = 0; r < 4; ++r) {
                    const int m = m0 + wr * 32 + mi * 16 + quad * 4 + r;
                    const float val = acc[mi][ni][r] + bn;
                    // head-major (B, HEADS, NV, HD)
                    const int b = m / NV, rr = m - b * NV;
                    const int h = n >> 5, c = n & 31;
                    vOut[(((size_t)b * HEADS + h) * NV + rr) * HD + c] = bf_of(val);
                }
            } else {
                if (n >= NQA) continue;
                const float bn = (n < NOFF) ? boff[n] : ba[n - NOFF];
                #pragma unroll
                for (int r = 0; r < 4; ++r) {
                    const int m = m0 + wr * 32 + mi * 16 + quad * 4 + r;
                    const float val = acc[mi][ni][r] + bn;
                    if (n < NOFF)
                        offOut[(size_t)m * NOFF + n] = bf_of(val);
                    else
                        aOut[(size_t)m * TP + (n - NOFF)] = bf_of(val);
                }
            }
        }
    }
}

// --- kernel 3: out = t @ Wo^T + bo (fp32 out). A = t_hi bf16 (g2lds staging,
// single product), B = Wo fp32 converted during staging. Flattened, n-fastest.
__global__ __launch_bounds__(256) void gemm_out_kernel(
    const u16* __restrict__ Ah,
    const float* __restrict__ Wo, const float* __restrict__ bias,
    float* __restrict__ Cout)
{
    __shared__ u16 sAh[GBM * GBK];
    __shared__ u16 sBh[GBN * GBK];

    const int bid = blockIdx.x;
    const int m0 = (bid >> 2) * GBM;
    const int n0 = (bid & 3) * GBN;

    const int tid  = threadIdx.x;
    const int lane = tid & 63;
    const int wave = tid >> 6;
    const int wr   = wave & 1;
    const int wc   = wave >> 1;
    const int qm   = lane & 15;
    const int quad = lane >> 4;

    // g2lds map for A (bf16): row = (wave<<4)+(lane>>2), k = (lane&3)*8
    const int arow = (wave << 4) + (lane >> 2);
    const int ak   = (lane & 3) * 8;
    // VALU map for B (fp32)
    const int srow = tid >> 2;
    const int sc   = (tid & 3) * 8;
    const float* Bsrc = Wo + (size_t)(n0 + srow) * CDIM;

    f32x4 acc[2][2];
    #pragma unroll
    for (int i = 0; i < 2; ++i)
        #pragma unroll
        for (int j = 0; j < 2; ++j)
            acc[i][j] = (f32x4){0.f, 0.f, 0.f, 0.f};

    for (int k0 = 0; k0 < CDIM; k0 += GBK) {
        const size_t ga = (size_t)(m0 + arow) * CDIM + k0 + ak;
        g2lds16(Ah + ga, sAh + wave * 512);
        const float4 b0 = *reinterpret_cast<const float4*>(&Bsrc[k0 + sc]);
        const float4 b1 = *reinterpret_cast<const float4*>(&Bsrc[k0 + sc + 4]);
        *reinterpret_cast<ushort4*>(&sBh[srow * GBK + sc])     = cvt_hi(b0);
        *reinterpret_cast<ushort4*>(&sBh[srow * GBK + sc + 4]) = cvt_hi(b1);
        __syncthreads();

        bf16x8 fah[2], fbh[2];
        #pragma unroll
        for (int x = 0; x < 2; ++x) {
            const int rm = wr * 32 + x * 16 + qm;
            const int rn = wc * 32 + x * 16 + qm;
            fah[x] = *reinterpret_cast<const bf16x8*>(&sAh[rm * GBK + quad * 8]);
            fbh[x] = *reinterpret_cast<const bf16x8*>(&sBh[rn * GBK + quad * 8]);
        }
        #pragma unroll
        for (int mi = 0; mi < 2; ++mi)
            #pragma unroll
            for (int ni = 0; ni < 2; ++ni)
                acc[mi][ni] = __builtin_amdgcn_mfma_f32_16x16x32_bf16(
                    fah[mi], fbh[ni], acc[mi][ni], 0, 0, 0);
        __syncthreads();
    }

    #pragma unroll
    for (int mi = 0; mi < 2; ++mi) {
        #pragma unroll
        for (int ni = 0; ni < 2; ++ni) {
            const int n = n0 + wc * 32 + ni * 16 + qm;
            const float bn = bias[n];
            #pragma unroll
            for (int r = 0; r < 4; ++r) {
                const int m = m0 + wr * 32 + mi * 16 + quad * 4 + r;
                Cout[(size_t)m * CDIM + n] = acc[mi][ni][r] + bn;
            }
        }
    }
}

// ---------------------------------------------------------------------------
// MSDA core v6 (unchanged from round 8): 4 queries/block, 64 threads/query =
// 8 heads x 4 channel-octets x 2 tap-replicas. dwordx4 gathers; shfl_xor(4)
// replica combine. Output t_hi only (bf16).
// ---------------------------------------------------------------------------
__global__ __launch_bounds__(256) void msda_core_kernel(
    const u16* __restrict__ off,    // (B*NQ, 192) bf16
    const u16* __restrict__ alog,   // (B*NQ, 96) bf16
    const float* __restrict__ refp, // (B*NQ, 2)
    const u16*   __restrict__ v,    // (B, HEADS, NV, HD) bf16
    u16* __restrict__ t_hi)         // (B*NQ, 256) bf16
{
    const int tid = threadIdx.x;
    const int bq0 = blockIdx.x * 4;

    __shared__ float s_w[4][TP];
    __shared__ int   s_idx[4][TP][4];   // spatial*64 byte offsets in head plane
    __shared__ float s_twt[4][TP][4];

    // logits for 4 queries (384 values)
    #pragma unroll
    for (int base = 0; base < 4 * TP; base += 256) {
        const int idx = base + tid;
        if (idx < 4 * TP) {
            const int q = idx / TP, j = idx - q * TP;
            s_w[q][j] = bf_back(alog[(size_t)(bq0 + q) * TP + j]);
        }
    }
    __syncthreads();

    // 32 softmaxes (4 queries x 8 heads)
    if (tid < 32) {
        const int q = tid >> 3, h = tid & 7;
        float mx = -1e30f;
        #pragma unroll
        for (int i = 0; i < 12; ++i) mx = fmaxf(mx, s_w[q][h * 12 + i]);
        float e[12];
        float sum = 0.f;
        #pragma unroll
        for (int i = 0; i < 12; ++i) {
            e[i] = expf(s_w[q][h * 12 + i] - mx);
            sum += e[i];
        }
        const float inv = 1.f / sum;
        #pragma unroll
        for (int i = 0; i < 12; ++i) s_w[q][h * 12 + i] = e[i] * inv;
    }
    __syncthreads();

    // taps for 4 queries (384 taps)
    #pragma unroll
    for (int base = 0; base < 4 * TP; base += 256) {
        const int idx = base + tid;
        if (idx < 4 * TP) {
            const int q = idx / TP, j = idx - q * TP;
            const int bq = bq0 + q;
            const int jj = j % 12;
            const int l  = jj >> 2;
            const int Wl    = (l == 0) ? 64 : (l == 1) ? 32 : 16;
            const int start = (l == 0) ? 0 : (l == 1) ? 4096 : 5120;

            const float refx = refp[(size_t)bq * 2 + 0];
            const float refy = refp[(size_t)bq * 2 + 1];
            const float ox = bf_back(off[(size_t)bq * NOFF + j * 2 + 0]);
            const float oy = bf_back(off[(size_t)bq * NOFF + j * 2 + 1]);
            const float lx = fminf(fmaxf(refx + ox, 0.f), 1.f) * (float)Wl - 0.5f;
            const float ly = fminf(fmaxf(refy + oy, 0.f), 1.f) * (float)Wl - 0.5f;
            const float fx0 = floorf(lx), fy0 = floorf(ly);
            const int   x0  = (int)fx0,   y0  = (int)fy0;
            const float wx1 = lx - fx0,   wy1 = ly - fy0;
            const float wx0 = 1.f - wx1,  wy0 = 1.f - wy1;
            const float aw  = s_w[q][j];

            #pragma unroll
            for (int k = 0; k < 4; ++k) {
                const int dx = k & 1, dy = k >> 1;
                const int xi = x0 + dx, yi = y0 + dy;
                const bool ok = (xi >= 0) & (xi < Wl) & (yi >= 0) & (yi < Wl);
                const int xc = min(max(xi, 0), Wl - 1);
                const int yc = min(max(yi, 0), Wl - 1);
                s_idx[q][j][k] = (start + yc * Wl + xc) * (HD * 2);  // 64 B rows
                const float wxy = (dx ? wx1 : wx0) * (dy ? wy1 : wy0);
                s_twt[q][j][k] = ok ? aw * wxy : 0.f;
            }
        }
    }
    __syncthreads();

    // gather: 64 threads per query
    const int qsel = tid >> 6;          // 0..3 (one wave per query)
    const int ht   = tid & 63;
    const int h    = ht >> 3;           // 0..7
    const int sub  = ht & 7;
    const int oct  = sub & 3;           // channels 8*oct .. 8*oct+7
    const int rep  = sub >> 2;          // replica 0/1 -> taps [6r, 6r+6)
    const int bq   = bq0 + qsel;
    const int b    = bq / NQ;
    const char* vb = (const char*)v + (((size_t)b * HEADS + h) * NV) * (HD * 2) + oct * 16;

    float acc[8] = {};
    #pragma unroll
    for (int g = 0; g < 3; ++g) {        // 3 groups x 2 taps x 4 corners = 8 loads
        uint4 raw[8];
        float wt[8];
        #pragma unroll
        for (int pp = 0; pp < 2; ++pp) {
            const int j = h * 12 + rep * 6 + g * 2 + pp;
            const int4   ix = *reinterpret_cast<const int4*>(&s_idx[qsel][j][0]);
            const float4 tw = *reinterpret_cast<const float4*>(&s_twt[qsel][j][0]);
            raw[pp * 4 + 0] = *reinterpret_cast<const uint4*>(vb + ix.x);
            raw[pp * 4 + 1] = *reinterpret_cast<const uint4*>(vb + ix.y);
            raw[pp * 4 + 2] = *reinterpret_cast<const uint4*>(vb + ix.z);
            raw[pp * 4 + 3] = *reinterpret_cast<const uint4*>(vb + ix.w);
            wt[pp * 4 + 0] = tw.x; wt[pp * 4 + 1] = tw.y;
            wt[pp * 4 + 2] = tw.z; wt[pp * 4 + 3] = tw.w;
        }
        #pragma unroll
        for (int k = 0; k < 8; ++k) {
            acc[0] += wt[k] * __uint_as_float(raw[k].x << 16);
            acc[1] += wt[k] * __uint_as_float(raw[k].x & 0xffff0000u);
            acc[2] += wt[k] * __uint_as_float(raw[k].y << 16);
            acc[3] += wt[k] * __uint_as_float(raw[k].y & 0xffff0000u);
            acc[4] += wt[k] * __uint_as_float(raw[k].z << 16);
            acc[5] += wt[k] * __uint_as_float(raw[k].z & 0xffff0000u);
            acc[6] += wt[k] * __uint_as_float(raw[k].w << 16);
            acc[7] += wt[k] * __uint_as_float(raw[k].w & 0xffff0000u);
        }
    }

    // combine the two tap-replicas (lanes differ in bit 2)
    #pragma unroll
    for (int c = 0; c < 8; ++c)
        acc[c] += __shfl_xor(acc[c], 4);

    if (rep == 0) {
        uint4 o;
        o.x = (u32)bf_of(acc[0]) | ((u32)bf_of(acc[1]) << 16);
        o.y = (u32)bf_of(acc[2]) | ((u32)bf_of(acc[3]) << 16);
        o.z = (u32)bf_of(acc[4]) | ((u32)bf_of(acc[5]) << 16);
        o.w = (u32)bf_of(acc[6]) | ((u32)bf_of(acc[7]) << 16);
        const size_t base = (size_t)bq * CDIM + h * HD + oct * 8;
        *reinterpret_cast<uint4*>(t_hi + base) = o;
    }
}

// ---------------------------------------------------------------------------
// Launch: 3 dispatches total.
// ---------------------------------------------------------------------------
extern "C" void kernel_launch(void* const* d_in, const int* in_sizes, int n_in,
                              void* d_out, int out_size, void* d_ws, size_t ws_size,
                              hipStream_t stream)
{
    const float* query = (const float*)d_in[0];   // (B,NQ,C)
    const float* refp  = (const float*)d_in[1];   // (B,NQ,2)
    const float* value = (const float*)d_in[2];   // (B,NV,C)
    const float* Wv    = (const float*)d_in[3];   // (C,C)
    const float* bv    = (const float*)d_in[4];
    const float* Woff  = (const float*)d_in[5];   // (192,C)
    const float* boff  = (const float*)d_in[6];
    const float* Wa    = (const float*)d_in[7];   // (96,C)
    const float* ba    = (const float*)d_in[8];
    const float* Wo    = (const float*)d_in[9];   // (C,C)
    const float* bo    = (const float*)d_in[10];
    float* out = (float*)d_out;

    // ---- workspace layout (all bf16) ----
    char* w = (char*)d_ws;
    const size_t SZ_T = (size_t)MROWS * CDIM * 2;     // 5.5 MB
    u16* v_bf16 = (u16*)(w);                          // head-major gather source
    u16* t_hi   = (u16*)(w + 1 * SZ_T);
    u16* ws_off = (u16*)(w + 2 * SZ_T);               // (MROWS,192) bf16
    u16* ws_a   = (u16*)(w + 2 * SZ_T + (size_t)MROWS * NOFF * 2);

    const dim3 blk(256);

    // 1) v-GEMM (bf16 head-major out) + qa-GEMM (bf16 off||a out), fp32 in
    gemm_vqa_kernel<<<dim3(VBLOCKS + (MROWS / GBM) * 5), blk, 0, stream>>>(
        value, Wv, bv, v_bf16,
        query, Woff, Wa, boff, ba, ws_off, ws_a);

    // 2) sampling core -> t_hi (bf16)
    msda_core_kernel<<<dim3(MROWS / 4), blk, 0, stream>>>(
        ws_off, ws_a, refp, v_bf16, t_hi);

    // 3) out = t @ Wo^T + bo (fp32 out)
    gemm_out_kernel<<<dim3((MROWS / GBM) * 4), blk, 0, stream>>>(
        t_hi, Wo, bo, out);
}